// Round 17
// baseline (215.474 us; speedup 1.0000x reference)
//
#include <hip/hip_runtime.h>
#include <math.h>

#define CC 96
#define BB 512
#define TT 512

// ---------------------------------------------------------------------------
// Kernel 0: column max of transitions and E[i][j] = exp(T[i][j]-maxT[j])
// ---------------------------------------------------------------------------
__global__ __launch_bounds__(128) void crf_prep(const float* __restrict__ trans,
                                                float* __restrict__ E,
                                                float* __restrict__ maxT) {
    int j = threadIdx.x;
    if (j < CC) {
        float m = -INFINITY;
        for (int i = 0; i < CC; ++i) m = fmaxf(m, trans[i * CC + j]);
        maxT[j] = m;
        for (int i = 0; i < CC; ++i) E[i * CC + j] = __expf(trans[i * CC + j] - m);
    }
}

// ---------------------------------------------------------------------------
// Kernel 0b: pack mask rows into bit-words (no per-step SMEM loads).
// ---------------------------------------------------------------------------
__global__ __launch_bounds__(64) void pack_mask(const int* __restrict__ mask,
                                                unsigned* __restrict__ mbits) {
    const int b = blockIdx.x;
    const int w = threadIdx.x;
    if (w < 16) {
        unsigned bits = 0u;
        for (int k = 0; k < 32; ++k)
            bits |= (mask[b * TT + w * 32 + k] ? 1u : 0u) << k;
        mbits[b * 16 + w] = bits;
    }
}

// ---------------------------------------------------------------------------
// Kernel 1: forward recurrence, linear space, COLUMN-split + shfl reduction.
// r16 CRASH post-mortem: j0 was 2*(24w+jp) -> up to 166: OOB E/maxT reads,
// OOB LDS writes past pb[2][96] (corrupted wsum), out-of-array emissions
// read at b=511 -> GPU fault. Correct: wave w owns 12 pairs, global pair
// = 12w+jp, j0 = 24w + 2*jp <= 94. ONLY that line changed vs r15.
// Structure: wave w owns j-columns [24w, 24w+24); lane (g=l>>4, jp=l&15):
// group g covers i-quarter [24g, 24g+24) for pair jp. Per step: 12 broadcast
// ds_read_b64 of group-g's p-quarter (uniform addrs, banks 0/24/16/8) +
// 24 pk_fma -> cross-group reduce via 2 shfl_xor hops (16,32) [replaces
// r14's pex LDS round-trip] -> q replicated -> scale -> owners (g==0)
// publish p -> ONE lgkm+barrier. Renorm every 8 steps with its own
// mini-barrier (amortized). Reduction tree order == r14 (numerics exact).
// Emissions prefetched 4 ahead; packed mask bits.
// ---------------------------------------------------------------------------
#define PKFMA_LO(A_, S_, E_) \
    asm("v_pk_fma_f32 %0, %1, %2, %0 op_sel:[0,0,0] op_sel_hi:[0,1,1]" \
        : "+v"(A_) : "v"(S_), "v"(E_))
#define PKFMA_HI(A_, S_, E_) \
    asm("v_pk_fma_f32 %0, %1, %2, %0 op_sel:[1,0,0] op_sel_hi:[1,1,1]" \
        : "+v"(A_) : "v"(S_), "v"(E_))

#define STEP(PF_, K_, BIT_, REN_) do {                                        \
    const int sl_ = (K_) & 3;                                                 \
    const int pr_ = (K_) & 1;                                                 \
    const float2 ce_ = es[sl_];                                               \
    es[sl_] = *(const float2*)(PF_);                                          \
    const float scx_ = __expf(mTx + ce_.x);                                   \
    const float scy_ = __expf(mTy + ce_.y);                                   \
    float2 a0={0.f,0.f}, a1={0.f,0.f}, a2={0.f,0.f}, a3={0.f,0.f};            \
    const float* src_ = &pb[pr_][24 * g];                                     \
    _Pragma("unroll")                                                         \
    for (int k_ = 0; k_ < 24; k_ += 4) {                                      \
        const float2 p0_ = *(const float2*)(src_ + k_);                       \
        const float2 p1_ = *(const float2*)(src_ + k_ + 2);                   \
        PKFMA_LO(a0, p0_, er[k_]);                                            \
        PKFMA_HI(a1, p0_, er[k_ + 1]);                                        \
        PKFMA_LO(a2, p1_, er[k_ + 2]);                                        \
        PKFMA_HI(a3, p1_, er[k_ + 3]);                                        \
    }                                                                         \
    float qx_ = (a0.x + a1.x) + (a2.x + a3.x);                                \
    float qy_ = (a0.y + a1.y) + (a2.y + a3.y);                                \
    qx_ += __shfl_xor(qx_, 16); qx_ += __shfl_xor(qx_, 32);                   \
    qy_ += __shfl_xor(qy_, 16); qy_ += __shfl_xor(qy_, 32);                   \
    if (BIT_) { prx = qx_ * scx_; pry = qy_ * scy_; }                         \
    if (REN_) {                                                               \
        float loc_ = act ? (prx + pry) : 0.f;                                 \
        loc_ += __shfl_xor(loc_, 1); loc_ += __shfl_xor(loc_, 2);             \
        loc_ += __shfl_xor(loc_, 4); loc_ += __shfl_xor(loc_, 8);             \
        if (l == 0) wsum[w] = loc_;                                           \
        asm volatile("s_waitcnt lgkmcnt(0)" ::: "memory");                    \
        __builtin_amdgcn_s_barrier();                                         \
        const float r_ = (wsum[0] + wsum[1]) + (wsum[2] + wsum[3]);           \
        const float inv_ = 1.0f / r_;                                         \
        prx *= inv_; pry *= inv_;                                             \
        S += (double)__logf(r_);                                              \
    }                                                                         \
    if (own) *(float2*)&pb[pr_ ^ 1][j0] = make_float2(prx, pry);              \
    asm volatile("s_waitcnt lgkmcnt(0)" ::: "memory");                        \
    __builtin_amdgcn_s_barrier();                                             \
} while (0)

__global__ __launch_bounds__(256, 2)
void crf_forward(const float* __restrict__ emissions,
                 const unsigned* __restrict__ mbits,
                 const float* __restrict__ start_t,
                 const float* __restrict__ end_t,
                 const float* __restrict__ E,
                 const float* __restrict__ maxT,
                 float* __restrict__ log_den) {
    const int b = blockIdx.x;
    const int w = threadIdx.x >> 6;       // wave: owns j-columns 24w..24w+23
    const int l = threadIdx.x & 63;
    const int g = l >> 4;                 // i-quarter group: i in [24g, 24g+24)
    const int jp = l & 15;                // j-pair within wave (active < 12)
    const bool act = (jp < 12);
    const int jpc = act ? jp : 11;        // clamped
    const int j0 = 24 * w + 2 * jpc;      // global state pair base (<= 94)  [r16 FIX]
    const bool own = (g == 0) && act;     // lanes that publish p

    __shared__ __align__(16) float pb[2][CC];   // broadcast p, by parity
    __shared__ float wsum[4];

    // E regs: er[k] = (E[i][j0], E[i][j0+1]), i = 24g + k  -> 48 VGPRs
    float2 er[24];
#pragma unroll
    for (int k = 0; k < 24; ++k)
        er[k] = *(const float2*)(E + (size_t)(24 * g + k) * CC + j0);

    const float* ep = emissions + (size_t)b * TT * CC + j0;
    const float mTx = maxT[j0];
    const float mTy = maxT[j0 + 1];

    // init t=0: p = exp(start + em0), replicated in all lanes of the pair
    float prx, pry;
    {
        const float2 e0 = *(const float2*)ep;
        prx = __expf(start_t[j0]     + e0.x);
        pry = __expf(start_t[j0 + 1] + e0.y);
    }
    double S = 0.0;
    if (own) *(float2*)&pb[1][j0] = make_float2(prx, pry);
    asm volatile("s_waitcnt lgkmcnt(0)" ::: "memory");
    __builtin_amdgcn_s_barrier();          // publish init (cross-wave reads)

    // emission prefetch slots: es[t&3] holds emission(t), t=1..4
    float2 es[4];
#pragma unroll
    for (int s = 1; s <= 4; ++s) es[s & 3] = *(const float2*)(ep + (size_t)s * CC);
    const float* pf = ep + (size_t)5 * CC;

    // head: t = 1..7
    const unsigned wb0 = mbits[b * 16];
#pragma unroll
    for (int k = 1; k < 8; ++k) {
        STEP(pf, k, (wb0 >> k) & 1u, 0);
        pf += CC;
    }
    // main: sb = 1..62 (t = 8*sb + k); renorm at k==0
    unsigned swc = wb0 >> 8;
    for (int sb = 1; sb < 63; ++sb) {
        const int sbn = sb + 1;
        const unsigned swn = mbits[b * 16 + (sbn >> 2)] >> ((sbn & 3) * 8);
#pragma unroll
        for (int k = 0; k < 8; ++k) {
            STEP(pf, k, (swc >> k) & 1u, k == 0);
            pf += CC;
        }
        swc = swn;
    }
    // tail: t = 504..511, prefetch clamped to t=511
#pragma unroll
    for (int k = 0; k < 8; ++k) {
        const int t_ = 504 + k;
        const int tn_ = (t_ + 4 <= TT - 1) ? (t_ + 4) : (TT - 1);
        STEP(ep + (size_t)tn_ * CC, k, (swc >> k) & 1u, k == 0);
    }

    // final: log_den = S + log(sum_j p[j] * exp(end[j]))
    float fx = own ? (prx * __expf(end_t[j0]) + pry * __expf(end_t[j0 + 1])) : 0.f;
#pragma unroll
    for (int off = 1; off < 64; off <<= 1) fx += __shfl_xor(fx, off);
    if (l == 0) wsum[w] = fx;
    __syncthreads();
    if (threadIdx.x == 0)
        log_den[b] = (float)(S + (double)__logf((wsum[0] + wsum[1]) + (wsum[2] + wsum[3])));
}

// ---------------------------------------------------------------------------
// Kernel 2: joint likelihood (numerator) — one block per batch.
// ---------------------------------------------------------------------------
__global__ __launch_bounds__(256) void crf_joint(const float* __restrict__ emissions,
                                                 const int* __restrict__ tags,
                                                 const int* __restrict__ mask,
                                                 const float* __restrict__ trans,
                                                 const float* __restrict__ start_t,
                                                 const float* __restrict__ end_t,
                                                 float* __restrict__ log_num) {
    const int b = blockIdx.x;
    const int tid = threadIdx.x;
    float s = 0.f;
    int mcount = 0;
    for (int t = tid; t < TT; t += 256) {
        int tg = tags[b * TT + t];
        float em = emissions[((size_t)b * TT + t) * CC + tg];
        int mk = mask[b * TT + t];
        mcount += mk;
        if (t == 0) {
            s += start_t[tg] + em;  // t=0 term unmasked in reference
        } else {
            int tp = tags[b * TT + t - 1];
            s += mk ? (trans[tp * CC + tg] + em) : 0.f;
        }
    }
    __shared__ float sred[4];
    __shared__ int mred[4];
#pragma unroll
    for (int off = 32; off; off >>= 1) {
        s += __shfl_xor(s, off);
        mcount += __shfl_xor(mcount, off);
    }
    if ((tid & 63) == 0) { sred[tid >> 6] = s; mred[tid >> 6] = mcount; }
    __syncthreads();
    if (tid == 0) {
        float tot = (sred[0] + sred[1]) + (sred[2] + sred[3]);
        int mt = (mred[0] + mred[1]) + (mred[2] + mred[3]);
        int last_tag = tags[b * TT + (mt - 1)];
        log_num[b] = tot + end_t[last_tag];
    }
}

// ---------------------------------------------------------------------------
// Kernel 3: final mean(log_den - log_num)
// ---------------------------------------------------------------------------
__global__ __launch_bounds__(512) void crf_final(const float* __restrict__ log_den,
                                                 const float* __restrict__ log_num,
                                                 float* __restrict__ out) {
    const int tid = threadIdx.x;
    float d = log_den[tid] - log_num[tid];
#pragma unroll
    for (int off = 32; off; off >>= 1) d += __shfl_xor(d, off);
    __shared__ float sred[8];
    if ((tid & 63) == 0) sred[tid >> 6] = d;
    __syncthreads();
    if (tid == 0) {
        float tot = 0.f;
        for (int w = 0; w < 8; ++w) tot += sred[w];
        out[0] = tot / (float)BB;
    }
}

extern "C" void kernel_launch(void* const* d_in, const int* in_sizes, int n_in,
                              void* d_out, int out_size, void* d_ws, size_t ws_size,
                              hipStream_t stream) {
    const float* emissions = (const float*)d_in[0];
    const int*   tags      = (const int*)d_in[1];
    const int*   mask      = (const int*)d_in[2];
    const float* trans     = (const float*)d_in[3];
    const float* start_t   = (const float*)d_in[4];
    const float* end_t     = (const float*)d_in[5];
    float* out = (float*)d_out;

    float*    ws      = (float*)d_ws;
    float*    E       = ws;               // 9216 floats
    float*    maxT    = ws + 9216;        // 96
    float*    log_den = ws + 9312;        // 512
    float*    log_num = ws + 9824;        // 512
    unsigned* mbits   = (unsigned*)(ws + 10336);  // 512*16 u32

    crf_prep<<<1, 128, 0, stream>>>(trans, E, maxT);
    pack_mask<<<BB, 64, 0, stream>>>(mask, mbits);
    crf_forward<<<BB, 256, 0, stream>>>(emissions, mbits, start_t, end_t, E, maxT, log_den);
    crf_joint<<<BB, 256, 0, stream>>>(emissions, tags, mask, trans, start_t, end_t, log_num);
    crf_final<<<1, 512, 0, stream>>>(log_den, log_num, out);
}